// Round 2
// baseline (23768.970 us; speedup 1.0000x reference)
//
#include <hip/hip_runtime.h>

#define NNODE 100000
#define NCLS  50000
#define NEDGE 400000
#define NDIM  43
#define CDIM  2
#define HID   128
#define NHEAD 4
#define CHN   32
#define NLAY  4

// ---------------------------------------------------------------------------
// Y[i][j] = B[j] + sum_k X[i][k]*W[k][j]   (all f32). K small (43/2).
__global__ void proj_kernel(const float* __restrict__ X, const float* __restrict__ W,
                            const float* __restrict__ B, float* __restrict__ Y,
                            int nrows, int K) {
  int t = blockIdx.x * blockDim.x + threadIdx.x;
  if (t >= nrows * HID) return;
  int i = t >> 7, j = t & (HID - 1);
  float acc = B[j];
  for (int k = 0; k < K; ++k)
    acc = fmaf(X[i * K + k], W[k * HID + j], acc);
  Y[t] = acc;
}

// ---------------------------------------------------------------------------
// Y[r][j] = B[j] + sum_k X[r][k]*W[k][j],  X f32 [nrows][128], W f32 [128][128].
// Block: 64 rows, 256 threads; per-thread tile 4 rows x 8 cols.
// K chunked 2x64: LDS = Ws 32KB + XsT 16KB = 48KB/block.
__global__ __launch_bounds__(256) void gemm128(const float* __restrict__ X,
                                               const float* __restrict__ W,
                                               const float* __restrict__ B,
                                               float* __restrict__ Y, int nrows) {
  __shared__ float Ws[64][HID];    // [k][j] chunk
  __shared__ float XsT[64][64];    // [k][r] chunk
  const int tid = threadIdx.x;
  const int row0 = blockIdx.x * 64;
  const int cg = tid & 15;   // 16 col groups -> j0 = cg*8
  const int rg = tid >> 4;   // 16 row groups -> r0 = rg*4
  const int j0 = cg * 8;
  const int r0 = rg * 4;

  float acc[4][8];
#pragma unroll
  for (int rr = 0; rr < 4; ++rr)
#pragma unroll
    for (int cc = 0; cc < 8; ++cc) acc[rr][cc] = 0.f;

  for (int kc = 0; kc < 2; ++kc) {
    const int k0 = kc * 64;
    // stage W chunk: 64x128 f32 = 2048 float4 (8 iters)
    for (int i = tid; i < 2048; i += 256) {
      int k = i >> 5;             // 32 float4 per row
      int j4 = (i & 31) << 2;
      *(float4*)&Ws[k][j4] = *(const float4*)&W[(size_t)(k0 + k) * HID + j4];
    }
    // stage X^T chunk: 64 rows x 64 k = 1024 float4 (4 iters)
    for (int i = tid; i < 1024; i += 256) {
      int r = i >> 4;             // 16 float4 per row
      int k4 = (i & 15) << 2;
      int gr = row0 + r;
      float4 v = make_float4(0.f, 0.f, 0.f, 0.f);
      if (gr < nrows) v = *(const float4*)&X[(size_t)gr * HID + k0 + k4];
      XsT[k4 + 0][r] = v.x;
      XsT[k4 + 1][r] = v.y;
      XsT[k4 + 2][r] = v.z;
      XsT[k4 + 3][r] = v.w;
    }
    __syncthreads();

#pragma unroll 8
    for (int k = 0; k < 64; ++k) {
      const float4 xv = *(const float4*)&XsT[k][r0];
      const float4 wa = *(const float4*)&Ws[k][j0];
      const float4 wb = *(const float4*)&Ws[k][j0 + 4];
      float w[8] = {wa.x, wa.y, wa.z, wa.w, wb.x, wb.y, wb.z, wb.w};
      float xx[4] = {xv.x, xv.y, xv.z, xv.w};
#pragma unroll
      for (int rr = 0; rr < 4; ++rr)
#pragma unroll
        for (int cc = 0; cc < 8; ++cc)
          acc[rr][cc] = fmaf(xx[rr], w[cc], acc[rr][cc]);
    }
    __syncthreads();
  }

  const float4 b0 = *(const float4*)&B[j0];
  const float4 b1 = *(const float4*)&B[j0 + 4];
  const float bv[8] = {b0.x, b0.y, b0.z, b0.w, b1.x, b1.y, b1.z, b1.w};

#pragma unroll
  for (int rr = 0; rr < 4; ++rr) {
    int gr = row0 + r0 + rr;
    if (gr < nrows) {
      float4 o0 = make_float4(acc[rr][0] + bv[0], acc[rr][1] + bv[1],
                              acc[rr][2] + bv[2], acc[rr][3] + bv[3]);
      float4 o1 = make_float4(acc[rr][4] + bv[4], acc[rr][5] + bv[5],
                              acc[rr][6] + bv[6], acc[rr][7] + bv[7]);
      *(float4*)&Y[(size_t)gr * HID + j0] = o0;
      *(float4*)&Y[(size_t)gr * HID + j0 + 4] = o1;
    }
  }
}

// ---------------------------------------------------------------------------
// Per (edge,head): score = att[h] . leaky_relu(xl[src]+xr[dst]); ex=exp(score);
// den[dst,h] += ex  (softmax WITHOUT max-subtraction: identical result, scores O(1)).
__global__ __launch_bounds__(256) void edge_score(const float* __restrict__ xl,
                                                  const float* __restrict__ xr,
                                                  const int* __restrict__ src,
                                                  const int* __restrict__ dst,
                                                  const float* __restrict__ att,
                                                  float* __restrict__ ex,
                                                  float* __restrict__ den) {
  __shared__ float attS[HID];
  if (threadIdx.x < HID) attS[threadIdx.x] = att[threadIdx.x];
  __syncthreads();
  int t = blockIdx.x * 256 + threadIdx.x;
  if (t >= NEDGE * NHEAD) return;
  int e = t >> 2, h = t & 3;
  int s = src[e], d = dst[e];
  const float4* pl = (const float4*)&xl[(size_t)s * HID + h * CHN];
  const float4* pr = (const float4*)&xr[(size_t)d * HID + h * CHN];
  const float4* pa = (const float4*)&attS[h * CHN];
  float sc = 0.f;
#pragma unroll
  for (int q = 0; q < 8; ++q) {
    float4 a = pl[q], b = pr[q], av = pa[q];
    float mx = a.x + b.x; mx = mx > 0.f ? mx : 0.2f * mx;
    float my = a.y + b.y; my = my > 0.f ? my : 0.2f * my;
    float mz = a.z + b.z; mz = mz > 0.f ? mz : 0.2f * mz;
    float mw = a.w + b.w; mw = mw > 0.f ? mw : 0.2f * mw;
    sc = fmaf(av.x, mx, sc); sc = fmaf(av.y, my, sc);
    sc = fmaf(av.z, mz, sc); sc = fmaf(av.w, mw, sc);
  }
  float e_ = __expf(sc);
  ex[t] = e_;
  atomicAdd(&den[(size_t)d * NHEAD + h], e_);
}

// ---------------------------------------------------------------------------
// Per (edge,head): alpha = ex/den[dst,h];  agg[dst,h,:] += alpha * xl[src,h,:]
__global__ __launch_bounds__(256) void edge_aggregate(const float* __restrict__ xl,
                                                      const int* __restrict__ src,
                                                      const int* __restrict__ dst,
                                                      const float* __restrict__ ex,
                                                      const float* __restrict__ den,
                                                      float* __restrict__ agg) {
  int t = blockIdx.x * 256 + threadIdx.x;
  if (t >= NEDGE * NHEAD) return;
  int e = t >> 2, h = t & 3;
  int s = src[e], d = dst[e];
  float alpha = ex[t] / den[(size_t)d * NHEAD + h];
  const float4* pl = (const float4*)&xl[(size_t)s * HID + h * CHN];
  float* pa = &agg[(size_t)d * HID + h * CHN];
#pragma unroll
  for (int q = 0; q < 8; ++q) {
    float4 v = pl[q];
    atomicAdd(&pa[q * 4 + 0], v.x * alpha);
    atomicAdd(&pa[q * 4 + 1], v.y * alpha);
    atomicAdd(&pa[q * 4 + 2], v.z * alpha);
    atomicAdd(&pa[q * 4 + 3], v.w * alpha);
  }
}

// ---------------------------------------------------------------------------
// x[row] = LN(x[row] + agg[row] + bias) * g + b   (one 64-lane wave per row)
__global__ __launch_bounds__(256) void resid_ln(float* __restrict__ x,
                                                const float* __restrict__ agg,
                                                const float* __restrict__ bias,
                                                const float* __restrict__ g,
                                                const float* __restrict__ b,
                                                int nrows) {
  int lane = threadIdx.x & 63;
  int row = blockIdx.x * 4 + (threadIdx.x >> 6);
  if (row >= nrows) return;
  size_t i0 = (size_t)row * HID + lane;
  size_t i1 = i0 + 64;
  float v0 = x[i0] + agg[i0] + bias[lane];
  float v1 = x[i1] + agg[i1] + bias[lane + 64];
  float s = v0 + v1, ss = v0 * v0 + v1 * v1;
#pragma unroll
  for (int off = 32; off > 0; off >>= 1) {
    s += __shfl_down(s, off);
    ss += __shfl_down(ss, off);
  }
  s = __shfl(s, 0);
  ss = __shfl(ss, 0);
  float mu = s * (1.0f / HID);
  float var = ss * (1.0f / HID) - mu * mu;
  float inv = rsqrtf(var + 1e-5f);
  x[i0] = (v0 - mu) * inv * g[lane] + b[lane];
  x[i1] = (v1 - mu) * inv * g[lane + 64] + b[lane + 64];
}

// ---------------------------------------------------------------------------
__global__ void colsum(const float* __restrict__ xc, float* __restrict__ acc) {
  int j = threadIdx.x;  // 128 threads
  int per = (NCLS + gridDim.x - 1) / gridDim.x;
  int r0 = blockIdx.x * per;
  int r1 = min(r0 + per, NCLS);
  float s = 0.f;
  for (int r = r0; r < r1; ++r) s += xc[(size_t)r * HID + j];
  atomicAdd(&acc[j], s);
}

__global__ void final_out(const float* __restrict__ acc, float* __restrict__ out) {
  int j = threadIdx.x;
  out[j] = acc[j] * (1.0f / NCLS);
}

// ---------------------------------------------------------------------------
extern "C" void kernel_launch(void* const* d_in, const int* in_sizes, int n_in,
                              void* d_out, int out_size, void* d_ws, size_t ws_size,
                              hipStream_t stream) {
  (void)in_sizes; (void)n_in; (void)out_size; (void)ws_size;
  const float* x_node     = (const float*)d_in[0];
  const float* x_class    = (const float*)d_in[1];
  const int* member_src   = (const int*)d_in[2];
  const int* member_dst   = (const int*)d_in[3];
  const int* contains_src = (const int*)d_in[4];
  const int* contains_dst = (const int*)d_in[5];
  const float* npw = (const float*)d_in[6];
  const float* npb = (const float*)d_in[7];
  const float* cpw = (const float*)d_in[8];
  const float* cpb = (const float*)d_in[9];
  const float* n2c_wl   = (const float*)d_in[10];
  const float* n2c_bl   = (const float*)d_in[11];
  const float* n2c_wr   = (const float*)d_in[12];
  const float* n2c_br   = (const float*)d_in[13];
  const float* n2c_att  = (const float*)d_in[14];
  const float* n2c_bias = (const float*)d_in[15];
  const float* c2n_wl   = (const float*)d_in[16];
  const float* c2n_bl   = (const float*)d_in[17];
  const float* c2n_wr   = (const float*)d_in[18];
  const float* c2n_br   = (const float*)d_in[19];
  const float* c2n_att  = (const float*)d_in[20];
  const float* c2n_bias = (const float*)d_in[21];
  const float* ln_cg = (const float*)d_in[22];
  const float* ln_cb = (const float*)d_in[23];
  const float* ln_ng = (const float*)d_in[24];
  const float* ln_nb = (const float*)d_in[25];

  float* ws  = (float*)d_ws;
  float* xn  = ws;                                  // NNODE*128
  float* xc  = xn  + (size_t)NNODE * HID;           // NCLS*128
  float* xl  = xc  + (size_t)NCLS * HID;            // NNODE*128 (src proj)
  float* xr  = xl  + (size_t)NNODE * HID;           // NNODE*128 (dst proj, reused as agg)
  float* ex  = xr  + (size_t)NNODE * HID;           // NEDGE*NHEAD
  float* den = ex  + (size_t)NEDGE * NHEAD;         // NNODE*NHEAD
  float* acc = den + (size_t)NNODE * NHEAD;         // 128

  const int EG = (NEDGE * NHEAD + 255) / 256;

  proj_kernel<<<(NNODE * HID + 255) / 256, 256, 0, stream>>>(x_node, npw, npb, xn, NNODE, NDIM);
  proj_kernel<<<(NCLS * HID + 255) / 256, 256, 0, stream>>>(x_class, cpw, cpb, xc, NCLS, CDIM);

  for (int l = 0; l < NLAY; ++l) {
    // ---- n2c: src=xn (NNODE), dst=xc (NCLS) ----
    gemm128<<<(NNODE + 63) / 64, 256, 0, stream>>>(xn, n2c_wl + l * HID * HID, n2c_bl + l * HID, xl, NNODE);
    gemm128<<<(NCLS + 63) / 64, 256, 0, stream>>>(xc, n2c_wr + l * HID * HID, n2c_br + l * HID, xr, NCLS);
    hipMemsetAsync(den, 0, (size_t)NCLS * NHEAD * sizeof(float), stream);
    edge_score<<<EG, 256, 0, stream>>>(xl, xr, member_src, member_dst, n2c_att + l * HID, ex, den);
    hipMemsetAsync(xr, 0, (size_t)NCLS * HID * sizeof(float), stream);
    edge_aggregate<<<EG, 256, 0, stream>>>(xl, member_src, member_dst, ex, den, xr);
    resid_ln<<<(NCLS + 3) / 4, 256, 0, stream>>>(xc, xr, n2c_bias + l * HID, ln_cg + l * HID, ln_cb + l * HID, NCLS);

    // ---- c2n: src=xc (NCLS), dst=xn (NNODE) ----
    gemm128<<<(NCLS + 63) / 64, 256, 0, stream>>>(xc, c2n_wl + l * HID * HID, c2n_bl + l * HID, xl, NCLS);
    gemm128<<<(NNODE + 63) / 64, 256, 0, stream>>>(xn, c2n_wr + l * HID * HID, c2n_br + l * HID, xr, NNODE);
    hipMemsetAsync(den, 0, (size_t)NNODE * NHEAD * sizeof(float), stream);
    edge_score<<<EG, 256, 0, stream>>>(xl, xr, contains_src, contains_dst, c2n_att + l * HID, ex, den);
    hipMemsetAsync(xr, 0, (size_t)NNODE * HID * sizeof(float), stream);
    edge_aggregate<<<EG, 256, 0, stream>>>(xl, contains_src, contains_dst, ex, den, xr);
    resid_ln<<<(NNODE + 3) / 4, 256, 0, stream>>>(xn, xr, c2n_bias + l * HID, ln_ng + l * HID, ln_nb + l * HID, NNODE);
  }

  hipMemsetAsync(acc, 0, HID * sizeof(float), stream);
  colsum<<<256, HID, 0, stream>>>(xc, acc);
  final_out<<<1, HID, 0, stream>>>(acc, (float*)d_out);
}

// Round 3
// 1990.942 us; speedup vs baseline: 11.9386x; 11.9386x over previous
//
#include <hip/hip_runtime.h>

#define NNODE 100000
#define NCLS  50000
#define NEDGE 400000
#define NDIM  43
#define CDIM  2
#define HID   128
#define NHEAD 4
#define CHN   32
#define NLAY  4

// ---------------------------------------------------------------------------
// Y[i][j] = B[j] + sum_k X[i][k]*W[k][j]   (all f32). K small (43/2).
__global__ void proj_kernel(const float* __restrict__ X, const float* __restrict__ W,
                            const float* __restrict__ B, float* __restrict__ Y,
                            int nrows, int K) {
  int t = blockIdx.x * blockDim.x + threadIdx.x;
  if (t >= nrows * HID) return;
  int i = t >> 7, j = t & (HID - 1);
  float acc = B[j];
  for (int k = 0; k < K; ++k)
    acc = fmaf(X[i * K + k], W[k * HID + j], acc);
  Y[t] = acc;
}

// ---------------------------------------------------------------------------
// Y[r][j] = B[j] + sum_k X[r][k]*W[k][j],  X f32 [nrows][128], W f32 [128][128].
// Block: 64 rows, 256 threads; per-thread tile 4 rows x 8 cols. K chunked 2x64.
__global__ __launch_bounds__(256) void gemm128(const float* __restrict__ X,
                                               const float* __restrict__ W,
                                               const float* __restrict__ B,
                                               float* __restrict__ Y, int nrows) {
  __shared__ float Ws[64][HID];    // [k][j] chunk
  __shared__ float XsT[64][64];    // [k][r] chunk
  const int tid = threadIdx.x;
  const int row0 = blockIdx.x * 64;
  const int cg = tid & 15;
  const int rg = tid >> 4;
  const int j0 = cg * 8;
  const int r0 = rg * 4;

  float acc[4][8];
#pragma unroll
  for (int rr = 0; rr < 4; ++rr)
#pragma unroll
    for (int cc = 0; cc < 8; ++cc) acc[rr][cc] = 0.f;

  for (int kc = 0; kc < 2; ++kc) {
    const int k0 = kc * 64;
    for (int i = tid; i < 2048; i += 256) {
      int k = i >> 5;
      int j4 = (i & 31) << 2;
      *(float4*)&Ws[k][j4] = *(const float4*)&W[(size_t)(k0 + k) * HID + j4];
    }
    for (int i = tid; i < 1024; i += 256) {
      int r = i >> 4;
      int k4 = (i & 15) << 2;
      int gr = row0 + r;
      float4 v = make_float4(0.f, 0.f, 0.f, 0.f);
      if (gr < nrows) v = *(const float4*)&X[(size_t)gr * HID + k0 + k4];
      XsT[k4 + 0][r] = v.x;
      XsT[k4 + 1][r] = v.y;
      XsT[k4 + 2][r] = v.z;
      XsT[k4 + 3][r] = v.w;
    }
    __syncthreads();

#pragma unroll 8
    for (int k = 0; k < 64; ++k) {
      const float4 xv = *(const float4*)&XsT[k][r0];
      const float4 wa = *(const float4*)&Ws[k][j0];
      const float4 wb = *(const float4*)&Ws[k][j0 + 4];
      float w[8] = {wa.x, wa.y, wa.z, wa.w, wb.x, wb.y, wb.z, wb.w};
      float xx[4] = {xv.x, xv.y, xv.z, xv.w};
#pragma unroll
      for (int rr = 0; rr < 4; ++rr)
#pragma unroll
        for (int cc = 0; cc < 8; ++cc)
          acc[rr][cc] = fmaf(xx[rr], w[cc], acc[rr][cc]);
    }
    __syncthreads();
  }

  const float4 b0 = *(const float4*)&B[j0];
  const float4 b1 = *(const float4*)&B[j0 + 4];
  const float bv[8] = {b0.x, b0.y, b0.z, b0.w, b1.x, b1.y, b1.z, b1.w};

#pragma unroll
  for (int rr = 0; rr < 4; ++rr) {
    int gr = row0 + r0 + rr;
    if (gr < nrows) {
      float4 o0 = make_float4(acc[rr][0] + bv[0], acc[rr][1] + bv[1],
                              acc[rr][2] + bv[2], acc[rr][3] + bv[3]);
      float4 o1 = make_float4(acc[rr][4] + bv[4], acc[rr][5] + bv[5],
                              acc[rr][6] + bv[6], acc[rr][7] + bv[7]);
      *(float4*)&Y[(size_t)gr * HID + j0] = o0;
      *(float4*)&Y[(size_t)gr * HID + j0 + 4] = o1;
    }
  }
}

// ---------------------------------------------------------------------------
// CSR build: histogram -> scan -> scatter
__global__ void hist_kernel(const int* __restrict__ dst, int* __restrict__ cnt) {
  int e = blockIdx.x * 256 + threadIdx.x;
  if (e < NEDGE) atomicAdd(&cnt[dst[e]], 1);
}

// block b covers 1024 elements (4/thread); pre[i] = exclusive prefix within block
__global__ __launch_bounds__(256) void scan_blocks(const int* __restrict__ cnt,
                                                   int* __restrict__ pre,
                                                   int* __restrict__ bsum, int n) {
  __shared__ int sdata[256];
  const int b = blockIdx.x, t = threadIdx.x;
  const int base = b * 1024 + t * 4;
  int v[4], s = 0;
#pragma unroll
  for (int q = 0; q < 4; ++q) {
    int i = base + q;
    v[q] = (i < n) ? cnt[i] : 0;
    s += v[q];
  }
  sdata[t] = s;
  __syncthreads();
  for (int off = 1; off < 256; off <<= 1) {
    int y = (t >= off) ? sdata[t - off] : 0;
    __syncthreads();
    sdata[t] += y;
    __syncthreads();
  }
  int run = sdata[t] - s;  // exclusive prefix of thread sums
  if (t == 255) bsum[b] = sdata[255];
#pragma unroll
  for (int q = 0; q < 4; ++q) {
    int i = base + q;
    if (i < n) pre[i] = run;
    run += v[q];
  }
}

// single block; nb <= 128
__global__ __launch_bounds__(128) void scan_partials(int* __restrict__ bsum, int nb) {
  __shared__ int sd[128];
  int t = threadIdx.x;
  int v = (t < nb) ? bsum[t] : 0;
  sd[t] = v;
  __syncthreads();
  for (int off = 1; off < 128; off <<= 1) {
    int y = (t >= off) ? sd[t - off] : 0;
    __syncthreads();
    sd[t] += y;
    __syncthreads();
  }
  if (t < nb) bsum[t] = sd[t] - v;  // exclusive
}

__global__ void finalize_rowptr(const int* __restrict__ pre, const int* __restrict__ bsum,
                                int* __restrict__ rowptr, int n) {
  int i = blockIdx.x * 256 + threadIdx.x;
  if (i < n) rowptr[i] = pre[i] + bsum[i >> 10];
  if (i == 0) rowptr[n] = NEDGE;
}

__global__ void scatter_csr(const int* __restrict__ src, const int* __restrict__ dst,
                            const int* __restrict__ rowptr, int* __restrict__ cursor,
                            int* __restrict__ csr_src) {
  int e = blockIdx.x * 256 + threadIdx.x;
  if (e >= NEDGE) return;
  int d = dst[e];
  int p = atomicAdd(&cursor[d], 1);
  csr_src[rowptr[d] + p] = src[e];
}

// ---------------------------------------------------------------------------
// Fused per-dst GATv2: score + segment-softmax + aggregate + residual + LN.
// One block (128 threads = one channel each) per dst row.
// out = sum_e ex_e * xl[src_e] / sum_e ex_e  (== softmax-weighted sum; no max-sub)
__global__ __launch_bounds__(128) void gat_dst(float* __restrict__ x,          // [n_dst][128] inout
                                               const float* __restrict__ xl,   // [n_src][128]
                                               const float* __restrict__ xr,   // [n_dst][128]
                                               const int* __restrict__ rowptr,
                                               const int* __restrict__ csr_src,
                                               const float* __restrict__ att,  // [128]
                                               const float* __restrict__ bias,
                                               const float* __restrict__ g,
                                               const float* __restrict__ b) {
  const int d = blockIdx.x;
  const int j = threadIdx.x;  // channel; head h = j>>5 (32-lane aligned groups)
  const float xrv = xr[(size_t)d * HID + j];
  const float attv = att[j];
  const int e0 = rowptr[d], e1 = rowptr[d + 1];

  float acc = 0.f, den = 0.f;
  for (int idx = e0; idx < e1; ++idx) {
    int s = csr_src[idx];
    float xlv = xl[(size_t)s * HID + j];
    float m = xlv + xrv;
    m = m > 0.f ? m : 0.2f * m;
    float p = attv * m;
    // sum over the 32 lanes of this head (xor masks <32 stay in the group)
    p += __shfl_xor(p, 16);
    p += __shfl_xor(p, 8);
    p += __shfl_xor(p, 4);
    p += __shfl_xor(p, 2);
    p += __shfl_xor(p, 1);
    float e_ = __expf(p);
    acc = fmaf(e_, xlv, acc);
    den += e_;
  }
  float outv = (e1 > e0) ? acc / den : 0.f;

  float v = x[(size_t)d * HID + j] + outv + bias[j];

  // LayerNorm across 128 threads (2 waves)
  __shared__ float red[2][2];
  float s1 = v, s2 = v * v;
#pragma unroll
  for (int off = 32; off > 0; off >>= 1) {
    s1 += __shfl_down(s1, off);
    s2 += __shfl_down(s2, off);
  }
  const int wid = j >> 6, lane = j & 63;
  if (lane == 0) { red[wid][0] = s1; red[wid][1] = s2; }
  __syncthreads();
  float ts1 = red[0][0] + red[1][0];
  float ts2 = red[0][1] + red[1][1];
  float mu = ts1 * (1.0f / HID);
  float var = ts2 * (1.0f / HID) - mu * mu;
  float inv = rsqrtf(var + 1e-5f);
  x[(size_t)d * HID + j] = (v - mu) * inv * g[j] + b[j];
}

// ---------------------------------------------------------------------------
__global__ void colsum(const float* __restrict__ xc, float* __restrict__ acc) {
  int j = threadIdx.x;  // 128 threads
  int per = (NCLS + gridDim.x - 1) / gridDim.x;
  int r0 = blockIdx.x * per;
  int r1 = min(r0 + per, NCLS);
  float s = 0.f;
  for (int r = r0; r < r1; ++r) s += xc[(size_t)r * HID + j];
  atomicAdd(&acc[j], s);
}

__global__ void final_out(const float* __restrict__ acc, float* __restrict__ out) {
  int j = threadIdx.x;
  out[j] = acc[j] * (1.0f / NCLS);
}

// ---------------------------------------------------------------------------
extern "C" void kernel_launch(void* const* d_in, const int* in_sizes, int n_in,
                              void* d_out, int out_size, void* d_ws, size_t ws_size,
                              hipStream_t stream) {
  (void)in_sizes; (void)n_in; (void)out_size; (void)ws_size;
  const float* x_node     = (const float*)d_in[0];
  const float* x_class    = (const float*)d_in[1];
  const int* member_src   = (const int*)d_in[2];
  const int* member_dst   = (const int*)d_in[3];
  const int* contains_src = (const int*)d_in[4];
  const int* contains_dst = (const int*)d_in[5];
  const float* npw = (const float*)d_in[6];
  const float* npb = (const float*)d_in[7];
  const float* cpw = (const float*)d_in[8];
  const float* cpb = (const float*)d_in[9];
  const float* n2c_wl   = (const float*)d_in[10];
  const float* n2c_bl   = (const float*)d_in[11];
  const float* n2c_wr   = (const float*)d_in[12];
  const float* n2c_br   = (const float*)d_in[13];
  const float* n2c_att  = (const float*)d_in[14];
  const float* n2c_bias = (const float*)d_in[15];
  const float* c2n_wl   = (const float*)d_in[16];
  const float* c2n_bl   = (const float*)d_in[17];
  const float* c2n_wr   = (const float*)d_in[18];
  const float* c2n_br   = (const float*)d_in[19];
  const float* c2n_att  = (const float*)d_in[20];
  const float* c2n_bias = (const float*)d_in[21];
  const float* ln_cg = (const float*)d_in[22];
  const float* ln_cb = (const float*)d_in[23];
  const float* ln_ng = (const float*)d_in[24];
  const float* ln_nb = (const float*)d_in[25];

  float* ws  = (float*)d_ws;
  float* xn  = ws;                                  // NNODE*128
  float* xc  = xn  + (size_t)NNODE * HID;           // NCLS*128
  float* xl  = xc  + (size_t)NCLS * HID;            // NNODE*128
  float* xr  = xl  + (size_t)NNODE * HID;           // NNODE*128
  float* acc = xr  + (size_t)NNODE * HID;           // 128
  int* ip        = (int*)(acc + 128);
  int* rowptr_c  = ip;                              // NCLS+1
  int* csr_c     = rowptr_c + (NCLS + 1);           // NEDGE
  int* rowptr_n  = csr_c + NEDGE;                   // NNODE+1
  int* csr_n     = rowptr_n + (NNODE + 1);          // NEDGE
  int* cnt       = csr_n + NEDGE;                   // NNODE (max)
  int* cursor    = cnt + NNODE;                     // NNODE
  int* pre       = cursor + NNODE;                  // NNODE
  int* bsum      = pre + NNODE;                     // 128

  const int EB = (NEDGE + 255) / 256;

  // ---- initial projections ----
  proj_kernel<<<(NNODE * HID + 255) / 256, 256, 0, stream>>>(x_node, npw, npb, xn, NNODE, NDIM);
  proj_kernel<<<(NCLS * HID + 255) / 256, 256, 0, stream>>>(x_class, cpw, cpb, xc, NCLS, CDIM);

  // ---- CSR build: member (dst=class) ----
  hipMemsetAsync(cnt, 0, NCLS * sizeof(int), stream);
  hipMemsetAsync(cursor, 0, NCLS * sizeof(int), stream);
  hist_kernel<<<EB, 256, 0, stream>>>(member_dst, cnt);
  scan_blocks<<<(NCLS + 1023) / 1024, 256, 0, stream>>>(cnt, pre, bsum, NCLS);
  scan_partials<<<1, 128, 0, stream>>>(bsum, (NCLS + 1023) / 1024);
  finalize_rowptr<<<(NCLS + 255) / 256, 256, 0, stream>>>(pre, bsum, rowptr_c, NCLS);
  scatter_csr<<<EB, 256, 0, stream>>>(member_src, member_dst, rowptr_c, cursor, csr_c);

  // ---- CSR build: contains (dst=node) ----
  hipMemsetAsync(cnt, 0, NNODE * sizeof(int), stream);
  hipMemsetAsync(cursor, 0, NNODE * sizeof(int), stream);
  hist_kernel<<<EB, 256, 0, stream>>>(contains_dst, cnt);
  scan_blocks<<<(NNODE + 1023) / 1024, 256, 0, stream>>>(cnt, pre, bsum, NNODE);
  scan_partials<<<1, 128, 0, stream>>>(bsum, (NNODE + 1023) / 1024);
  finalize_rowptr<<<(NNODE + 255) / 256, 256, 0, stream>>>(pre, bsum, rowptr_n, NNODE);
  scatter_csr<<<EB, 256, 0, stream>>>(contains_src, contains_dst, rowptr_n, cursor, csr_n);

  // ---- layers ----
  for (int l = 0; l < NLAY; ++l) {
    // n2c: src=xn (NNODE), dst=xc (NCLS)
    gemm128<<<(NNODE + 63) / 64, 256, 0, stream>>>(xn, n2c_wl + l * HID * HID, n2c_bl + l * HID, xl, NNODE);
    gemm128<<<(NCLS + 63) / 64, 256, 0, stream>>>(xc, n2c_wr + l * HID * HID, n2c_br + l * HID, xr, NCLS);
    gat_dst<<<NCLS, 128, 0, stream>>>(xc, xl, xr, rowptr_c, csr_c,
                                      n2c_att + l * HID, n2c_bias + l * HID,
                                      ln_cg + l * HID, ln_cb + l * HID);

    // c2n: src=xc (NCLS), dst=xn (NNODE)
    gemm128<<<(NCLS + 63) / 64, 256, 0, stream>>>(xc, c2n_wl + l * HID * HID, c2n_bl + l * HID, xl, NCLS);
    gemm128<<<(NNODE + 63) / 64, 256, 0, stream>>>(xn, c2n_wr + l * HID * HID, c2n_br + l * HID, xr, NNODE);
    gat_dst<<<NNODE, 128, 0, stream>>>(xn, xl, xr, rowptr_n, csr_n,
                                       c2n_att + l * HID, c2n_bias + l * HID,
                                       ln_ng + l * HID, ln_nb + l * HID);
  }

  hipMemsetAsync(acc, 0, HID * sizeof(float), stream);
  colsum<<<256, HID, 0, stream>>>(xc, acc);
  final_out<<<1, HID, 0, stream>>>(acc, (float*)d_out);
}